// Round 13
// baseline (502.074 us; speedup 1.0000x reference)
//
#include <hip/hip_runtime.h>
#include <hip/hip_bf16.h>

#define EPSV 1e-5f

constexpr int B_ = 16, C_ = 256;
constexpr int OHW_ = 49 * 49;          // 2401
constexpr int NTOT = 256 * 16 * 16;    // 65536
constexpr int GROUPS = 32, CPERG = 8;

typedef short bf16x8 __attribute__((ext_vector_type(8)));
typedef float f32x4 __attribute__((ext_vector_type(4)));

// ---------------- workspace layout (float offsets) ----------------
constexpr size_t OFF_S1 = 0;                               // conv1 out, 16*256*4096 f32
constexpr size_t SZ_S1  = (size_t)16 * 256 * 4096;
constexpr size_t OFF_T2 = OFF_S1 + SZ_S1;                  // conv2 out (bn'd in place)
constexpr size_t SZ_T2  = (size_t)16 * 256 * 256;
constexpr size_t OFF_ST = OFF_T2 + SZ_T2;                  // stats block (2048 f)
constexpr size_t OFF_Z  = OFF_ST + 2048;                   // [2][16][4096] z, z2
constexpr size_t OFF_C  = OFF_Z + 131072;                  // overlaid big region
constexpr size_t SPC_BYTES = (size_t)16 * 66 * 66 * 256 * 2;
constexpr size_t TPC_BYTES = (size_t)16 * 18 * 18 * 256 * 2;
constexpr size_t WR_BYTES  = (size_t)9 * 256 * 256 * 2;
constexpr size_t CPOFF = 0;
constexpr size_t NCOFF = CPOFF + (size_t)GROUPS * 16 * OHW_;
constexpr size_t SATOFF = NCOFF + (size_t)16 * OHW_;

// ---------------- async global->LDS 16B ----------------
__device__ __forceinline__ void gload_lds16(const void* g, void* l) {
    __builtin_amdgcn_global_load_lds((const __attribute__((address_space(1))) unsigned int*)g,
                                     (__attribute__((address_space(3))) unsigned int*)l,
                                     16, 0, 0);
}

// ---------------- pad + NCHW->NHWC + bf16 + weight reorg, merged ----------------
template<int W>
__device__ __forceinline__ void pad_body(int bid, const float* __restrict__ in,
                                         __hip_bfloat16* __restrict__ outp, float* tile)
{
    constexpr int PW = W + 2;
    int icg = bid & 3; bid >>= 2;
    int yp = bid % PW; bid /= PW;
    int b = bid;
    int ic0 = icg * 64;
    int tid = threadIdx.x;
    bool interior = (yp >= 1 && yp <= W);
    if (interior) {
        int y = yp - 1;
        for (int idx = tid; idx < 64 * W; idx += 256) {
            int i = idx / W, x = idx % W;
            tile[i * (W + 1) + x] = in[(((size_t)(b * C_ + ic0 + i)) * W + y) * W + x];
        }
    }
    __syncthreads();
    for (int idx = tid; idx < PW * 16; idx += 256) {
        int xp = idx >> 4, i4 = idx & 15;
        ushort4 v = make_ushort4(0, 0, 0, 0);
        if (interior && xp >= 1 && xp <= W) {
            #pragma unroll
            for (int k = 0; k < 4; ++k) {
                __hip_bfloat16 h = __float2bfloat16(tile[(i4 * 4 + k) * (W + 1) + xp - 1]);
                reinterpret_cast<unsigned short*>(&v)[k] = *reinterpret_cast<unsigned short*>(&h);
            }
        }
        *reinterpret_cast<ushort4*>(&outp[(((size_t)(b * PW) + yp) * PW + xp) * 256 + ic0 + i4 * 4]) = v;
    }
}

__global__ __launch_bounds__(256)
void pad_all(const float* __restrict__ s, const float* __restrict__ t,
             __hip_bfloat16* __restrict__ SPc, __hip_bfloat16* __restrict__ TPc,
             const float* __restrict__ w1, const float* __restrict__ w2,
             __hip_bfloat16* __restrict__ wr1, __hip_bfloat16* __restrict__ wr2)
{
    __shared__ float tile[64 * 65];
    constexpr int NP1 = 16 * 66 * 4, NP2 = 16 * 18 * 4;
    int bid = blockIdx.x;
    if (bid < NP1) { pad_body<64>(bid, s, SPc, tile); return; }
    bid -= NP1;
    if (bid < NP2) { pad_body<16>(bid, t, TPc, tile); return; }
    bid -= NP2;
    const float* w = (bid < 256) ? w1 : w2;
    __hip_bfloat16* wr = (bid < 256) ? wr1 : wr2;
    int idx = (bid & 255) * 256 + threadIdx.x;
    const float* src = w + (size_t)idx * 9;
    #pragma unroll
    for (int t_ = 0; t_ < 9; ++t_)
        wr[(size_t)t_ * 65536 + idx] = __float2bfloat16(src[t_]);
}

// ---------------- conv implicit GEMM MFMA — R9-exact body (single-buf, drain->compute) ----------------
template<int W>
__device__ __forceinline__ void conv_body(
    int logical,
    const __hip_bfloat16* __restrict__ SPc, const __hip_bfloat16* __restrict__ Wr,
    const float* __restrict__ bias, float* __restrict__ out,
    float* __restrict__ csum, float* __restrict__ csq,
    __hip_bfloat16* A_lds, __hip_bfloat16* B_lds)
{
    constexpr int PW = W + 2;
    constexpr int NPIX = W * W;
    constexpr int NT = NPIX / 128;
    int nt = logical % NT; logical /= NT;
    int mt = logical & 1;  logical >>= 1;
    int b  = logical;
    int tid = threadIdx.x;
    int lane = tid & 63;
    int wv = tid >> 6, wm = wv >> 1, wn = wv & 1;
    int oc0 = mt * 128, p0 = nt * 128;

    f32x4 acc[4][4];
    #pragma unroll
    for (int i = 0; i < 4; ++i)
        #pragma unroll
        for (int j = 0; j < 4; ++j)
            #pragma unroll
            for (int r = 0; r < 4; ++r) acc[i][j][r] = 0.f;

    const bf16x8* Af = reinterpret_cast<const bf16x8*>(A_lds);
    const bf16x8* Bf = reinterpret_cast<const bf16x8*>(B_lds);
    int colb = lane >> 4;
    int rA = lane & 15;

    for (int kc = 0; kc < 72; ++kc) {
        int tap = kc >> 3, icc = kc & 7;
        int ic0 = icc * 32;
        int dy = tap / 3, dx = tap - dy * 3;
        __syncthreads();
        #pragma unroll
        for (int it = 0; it < 2; ++it) {
            int sIdx = tid + it * 256;
            int row = sIdx >> 2, seg = sIdx & 3;
            const __hip_bfloat16* srcA =
                Wr + ((size_t)(tap * 256 + oc0 + row)) * 256 + ic0 + seg * 8;
            gload_lds16(srcA, &A_lds[sIdx * 8]);
            int p = p0 + row;
            int y = p / W, x = p % W;
            const __hip_bfloat16* srcB =
                SPc + (((size_t)(b * PW + y + dy)) * PW + x + dx) * 256 + ic0 + seg * 8;
            gload_lds16(srcB, &B_lds[sIdx * 8]);
        }
        asm volatile("s_waitcnt vmcnt(0)" ::: "memory");
        __syncthreads();

        bf16x8 a[4], bb[4];
        #pragma unroll
        for (int mi = 0; mi < 4; ++mi)
            a[mi] = Af[(wm * 64 + mi * 16 + rA) * 4 + colb];
        #pragma unroll
        for (int ni = 0; ni < 4; ++ni)
            bb[ni] = Bf[(wn * 64 + ni * 16 + rA) * 4 + colb];
        #pragma unroll
        for (int mi = 0; mi < 4; ++mi)
            #pragma unroll
            for (int ni = 0; ni < 4; ++ni)
                acc[mi][ni] = __builtin_amdgcn_mfma_f32_16x16x32_bf16(
                    a[mi], bb[ni], acc[mi][ni], 0, 0, 0);
    }

    #pragma unroll
    for (int mi = 0; mi < 4; ++mi) {
        int ocb = oc0 + wm * 64 + mi * 16 + colb * 4;
        #pragma unroll
        for (int r = 0; r < 4; ++r) {
            int oc = ocb + r;
            float bv = bias[oc];
            float* orow = out + ((size_t)(b * C_ + oc)) * NPIX;
            float s_oc = 0.f, q_oc = 0.f;
            #pragma unroll
            for (int ni = 0; ni < 4; ++ni) {
                int px = p0 + wn * 64 + ni * 16 + rA;
                float v = acc[mi][ni][r] + bv;
                orow[px] = v;
                s_oc += v; q_oc += v * v;
            }
            #pragma unroll
            for (int m_ = 1; m_ < 16; m_ <<= 1) {
                s_oc += __shfl_xor(s_oc, m_);
                q_oc += __shfl_xor(q_oc, m_);
            }
            if (rA == 0) {
                atomicAdd(&csum[oc], s_oc);
                atomicAdd(&csq[oc], q_oc);
            }
        }
    }
}

// conv2 blocks FIRST (bid<64): co-resident from t=0, latency hidden under conv1
__global__ __launch_bounds__(256)
void conv_all(const __hip_bfloat16* __restrict__ SPc, const __hip_bfloat16* __restrict__ Wr1,
              const float* __restrict__ b1, float* __restrict__ S1,
              float* __restrict__ CHS1, float* __restrict__ CHQ1,
              const __hip_bfloat16* __restrict__ TPc, const __hip_bfloat16* __restrict__ Wr2,
              const float* __restrict__ b2, float* __restrict__ T2,
              float* __restrict__ CHS2, float* __restrict__ CHQ2)
{
    __shared__ __hip_bfloat16 A_lds[4096];
    __shared__ __hip_bfloat16 B_lds[4096];
    int bid = blockIdx.x;
    if (bid < 64) {
        conv_body<16>(bid, TPc, Wr2, b2, T2, CHS2, CHQ2, A_lds, B_lds);
    } else {
        int l = bid - 64;
        int logical = (l & 7) * 128 + (l >> 3);   // bijective XCD remap (1024 % 8 == 0)
        conv_body<64>(logical, SPc, Wr1, b1, S1, CHS1, CHQ1, A_lds, B_lds);
    }
}

// ---------------- block reduce helper ----------------
__device__ inline void blk_reduce2(float& a, float& q, int tid) {
    #pragma unroll
    for (int off = 32; off > 0; off >>= 1) {
        a += __shfl_down(a, off);
        q += __shfl_down(q, off);
    }
    __shared__ float ra[4], rq[4];
    if ((tid & 63) == 0) { ra[tid >> 6] = a; rq[tid >> 6] = q; }
    __syncthreads();
    if (tid == 0) { a = ra[0] + ra[1] + ra[2] + ra[3]; q = rq[0] + rq[1] + rq[2] + rq[3]; }
}

// ---------------- BN2 normalize + template stats ----------------
__global__ __launch_bounds__(256)
void bn_t2_stats(float* __restrict__ T2, const float* __restrict__ csum,
                 const float* __restrict__ csq, const float* __restrict__ g2,
                 const float* __restrict__ be2, float* __restrict__ tmean,
                 float* __restrict__ ttstd)
{
    __shared__ float SC[256], SH[256];
    int b = blockIdx.x, tid = threadIdx.x;
    {
        float m = csum[tid] * (1.f / 4096.f);
        float v = csq[tid] * (1.f / 4096.f) - m * m;
        float sc = rsqrtf(v + EPSV) * g2[tid];
        SC[tid] = sc; SH[tid] = be2[tid] - m * sc;
    }
    __syncthreads();
    float4* p = reinterpret_cast<float4*>(T2 + (size_t)b * NTOT);
    float s = 0.f, q = 0.f;
    for (int i4 = tid; i4 < NTOT / 4; i4 += 256) {
        int c = i4 >> 6;
        float sc = SC[c], sh = SH[c];
        float4 v = p[i4];
        v.x = v.x * sc + sh; v.y = v.y * sc + sh;
        v.z = v.z * sc + sh; v.w = v.w * sc + sh;
        s += v.x + v.y + v.z + v.w;
        q += v.x * v.x + v.y * v.y + v.z * v.z + v.w * v.w;
        p[i4] = v;
    }
    blk_reduce2(s, q, tid);
    if (tid == 0) {
        float m = s / (float)NTOT;
        tmean[b] = m;
        ttstd[b] = sqrtf(fmaxf(q - (float)NTOT * m * m, 0.f) / (float)(NTOT - 1));
    }
}

// ---------------- cross-correlation + fused z/z2 partials (3 blocks/CU) ----------------
__global__ __launch_bounds__(256, 3)
void cross_v3(const float* __restrict__ s1, const float* __restrict__ t2,
              const float* __restrict__ csum, const float* __restrict__ csq,
              const float* __restrict__ g1, const float* __restrict__ be1,
              float* __restrict__ cpart, float* __restrict__ z)
{
    __shared__ float4 spl4[1024];            // 16 KB
    __shared__ float tpl[256];               // 1 KB
    __shared__ float red[2][64][49];         // 24.5 KB (two-step phase reduction)

    int g = blockIdx.x & (GROUPS - 1);
    int b = blockIdx.x / GROUPS;
    int tid = threadIdx.x;
    int phase = tid >> 6;
    int lane = tid & 63;
    int i = lane;
    int i_ld = i < 49 ? i : 48;

    float acc[49];
    #pragma unroll
    for (int j = 0; j < 49; ++j) acc[j] = 0.f;
    float4 zs[4], zq[4];
    #pragma unroll
    for (int k = 0; k < 4; ++k) {
        zs[k] = make_float4(0.f, 0.f, 0.f, 0.f);
        zq[k] = make_float4(0.f, 0.f, 0.f, 0.f);
    }

    #pragma unroll 1
    for (int cc = 0; cc < CPERG; ++cc) {
        int c = g * CPERG + cc;
        float m = csum[c] * (1.f / 65536.f);
        float v = csq[c] * (1.f / 65536.f) - m * m;
        float sc = rsqrtf(v + EPSV) * g1[c];
        float sh = be1[c] - m * sc;
        __syncthreads();
        const float4* sp4 = reinterpret_cast<const float4*>(s1 + ((size_t)(b * C_ + c)) * 4096);
        #pragma unroll
        for (int k = 0; k < 4; ++k) {
            int gidx = tid + k * 256;
            float4 val = sp4[gidx];
            val.x = val.x * sc + sh; val.y = val.y * sc + sh;
            val.z = val.z * sc + sh; val.w = val.w * sc + sh;
            zs[k].x += val.x; zs[k].y += val.y; zs[k].z += val.z; zs[k].w += val.w;
            zq[k].x += val.x * val.x; zq[k].y += val.y * val.y;
            zq[k].z += val.z * val.z; zq[k].w += val.w * val.w;
            int row = gidx >> 4, jg = gidx & 15;
            spl4[row * 16 + (jg ^ (row & 7))] = val;
        }
        tpl[tid] = t2[((size_t)(b * C_ + c)) * 256 + tid];
        __syncthreads();
        #pragma unroll 1
        for (int tyl = 0; tyl < 4; ++tyl) {
            int ty = phase * 4 + tyl;
            int row = i_ld + ty;
            float r_[64];
            #pragma unroll
            for (int jg = 0; jg < 16; ++jg) {
                float4 v4 = spl4[row * 16 + (jg ^ (row & 7))];
                r_[jg * 4 + 0] = v4.x; r_[jg * 4 + 1] = v4.y;
                r_[jg * 4 + 2] = v4.z; r_[jg * 4 + 3] = v4.w;
            }
            float tt[16];
            const float4* tp4 = reinterpret_cast<const float4*>(&tpl[ty * 16]);
            #pragma unroll
            for (int k = 0; k < 4; ++k) {
                float4 tv = tp4[k];
                tt[k * 4 + 0] = tv.x; tt[k * 4 + 1] = tv.y;
                tt[k * 4 + 2] = tv.z; tt[k * 4 + 3] = tv.w;
            }
            #pragma unroll
            for (int tx = 0; tx < 16; ++tx)
                #pragma unroll
                for (int j = 0; j < 49; ++j)
                    acc[j] += tt[tx] * r_[j + tx];
        }
    }
    #pragma unroll
    for (int k = 0; k < 4; ++k) {
        int pxb = (tid + k * 256) * 4;
        float* zb  = z + (size_t)b * 4096 + pxb;
        float* z2b = z + 65536 + (size_t)b * 4096 + pxb;
        atomicAdd(&zb[0], zs[k].x);  atomicAdd(&zb[1], zs[k].y);
        atomicAdd(&zb[2], zs[k].z);  atomicAdd(&zb[3], zs[k].w);
        atomicAdd(&z2b[0], zq[k].x); atomicAdd(&z2b[1], zq[k].y);
        atomicAdd(&z2b[2], zq[k].z); atomicAdd(&z2b[3], zq[k].w);
    }
    // two-step phase reduction into red[2]
    __syncthreads();
    if (i < 49 && phase < 2) {
        #pragma unroll
        for (int j = 0; j < 49; ++j) red[phase][i][j] = acc[j];
    }
    __syncthreads();
    if (i < 49 && phase >= 2) {
        #pragma unroll
        for (int j = 0; j < 49; ++j) red[phase - 2][i][j] += acc[j];
    }
    __syncthreads();
    float* dst = cpart + ((size_t)(g * B_ + b)) * OHW_;
    for (int e = tid; e < OHW_; e += 256) {
        int ii = e / 49, jj = e - ii * 49;
        dst[e] = red[0][ii][jj] + red[1][ii][jj];
    }
}

// ---------------- integral images ----------------
__global__ __launch_bounds__(256)
void sat_kernel(const float* __restrict__ zin, float* __restrict__ sat)
{
    __shared__ float t[65][66];
    int pl = blockIdx.x;
    int tid = threadIdx.x;
    const float* src = zin + (size_t)pl * 4096;
    for (int idx = tid; idx < 4096; idx += 256) {
        int y = idx >> 6, x = idx & 63;
        t[y + 1][x + 1] = src[idx];
    }
    for (int idx = tid; idx < 65; idx += 256) { t[0][idx] = 0.f; t[idx][0] = 0.f; }
    __syncthreads();
    if (tid < 64) {
        float run = 0.f;
        for (int x = 1; x <= 64; ++x) { run += t[tid + 1][x]; t[tid + 1][x] = run; }
    }
    __syncthreads();
    if (tid < 64) {
        float run = 0.f;
        for (int y = 1; y <= 64; ++y) { run += t[y][tid + 1]; t[y][tid + 1] = run; }
    }
    __syncthreads();
    float* dst = sat + (size_t)pl * 4225;
    for (int idx = tid; idx < 4225; idx += 256) {
        int r = idx / 65, c = idx % 65;
        dst[idx] = t[r][c];
    }
}

// ---------------- NCC assembly via SAT + global stats ----------------
__global__ __launch_bounds__(256)
void ncc_kernel(const float* __restrict__ cpart, const float* __restrict__ sat,
                const float* __restrict__ tmean, const float* __restrict__ ttstd,
                float* __restrict__ ncc, float* __restrict__ s3)
{
    int idx = blockIdx.x * 256 + threadIdx.x;
    float val = 0.f;
    if (idx < B_ * OHW_) {
        int b = idx / OHW_, r = idx - b * OHW_;
        int i = r / 49, j = r - i * 49;
        float cr = 0.f;
        #pragma unroll 4
        for (int g = 0; g < GROUPS; ++g) cr += cpart[((size_t)(g * B_ + b)) * OHW_ + r];
        const float* sz = sat + (size_t)b * 4225;
        const float* sq = sat + (size_t)(16 + b) * 4225;
        int a00 = i * 65 + j, a01 = i * 65 + j + 16;
        int a10 = (i + 16) * 65 + j, a11 = (i + 16) * 65 + j + 16;
        float wsum = sz[a11] - sz[a01] - sz[a10] + sz[a00];
        float wq   = sq[a11] - sq[a01] - sq[a10] + sq[a00];
        float crosst = cr - tmean[b] * wsum;
        float ssvar = fmaxf(wq - wsum * wsum * (1.f / 65536.f), 0.f) * (1.f / 65535.f);
        float ssstd = sqrtf(ssvar);
        val = crosst / (65536.f * ttstd[b] * ssstd);
        ncc[idx] = val;
    }
    float s = val, q = val * val;
    blk_reduce2(s, q, threadIdx.x);
    if (threadIdx.x == 0) { atomicAdd(&s3[0], s); atomicAdd(&s3[1], q); }
}

// ---------------- conv3+BN3+relu+conv4 ----------------
__global__ __launch_bounds__(256)
void final_kernel(const float* __restrict__ ncc, const float* __restrict__ s3,
                  const float* __restrict__ w3, const float* __restrict__ b3,
                  const float* __restrict__ g3, const float* __restrict__ be3,
                  const float* __restrict__ w4, const float* __restrict__ b4,
                  float* __restrict__ out)
{
    int idx = blockIdx.x * 256 + threadIdx.x;
    if (idx >= B_ * OHW_) return;
    constexpr float M = (float)(B_ * OHW_);
    float mn = s3[0] / M;
    float vn = s3[1] / M - mn * mn;
    float W3 = w3[0], B3 = b3[0];
    float my = W3 * mn + B3;
    float vy = W3 * W3 * vn;
    float sc = rsqrtf(vy + EPSV) * g3[0];
    float y = (W3 * ncc[idx] + B3 - my) * sc + be3[0];
    float h = fmaxf(y, 0.f);
    int b = idx / OHW_, r = idx - b * OHW_;
    out[((size_t)(b * 2 + 0)) * OHW_ + r] = h * w4[0] + b4[0];
    out[((size_t)(b * 2 + 1)) * OHW_ + r] = h * w4[1] + b4[1];
}

extern "C" void kernel_launch(void* const* d_in, const int* in_sizes, int n_in,
                              void* d_out, int out_size, void* d_ws, size_t ws_size,
                              hipStream_t stream)
{
    const float* s   = (const float*)d_in[0];
    const float* t   = (const float*)d_in[1];
    const float* w1  = (const float*)d_in[2];
    const float* b1  = (const float*)d_in[3];
    const float* g1  = (const float*)d_in[4];
    const float* be1 = (const float*)d_in[5];
    const float* w2  = (const float*)d_in[6];
    const float* b2  = (const float*)d_in[7];
    const float* g2  = (const float*)d_in[8];
    const float* be2 = (const float*)d_in[9];
    const float* w3  = (const float*)d_in[10];
    const float* b3  = (const float*)d_in[11];
    const float* g3  = (const float*)d_in[12];
    const float* be3 = (const float*)d_in[13];
    const float* w4  = (const float*)d_in[14];
    const float* b4  = (const float*)d_in[15];

    float* ws = (float*)d_ws;
    float* S1 = ws + OFF_S1;
    float* T2 = ws + OFF_T2;
    float* ST = ws + OFF_ST;
    float* CHS1 = ST + 0;
    float* CHQ1 = ST + 256;
    float* CHS2 = ST + 512;
    float* CHQ2 = ST + 768;
    float* S3   = ST + 1024;
    float* TM   = ST + 1040;
    float* TSD  = ST + 1056;
    float* Z    = ws + OFF_Z;

    char* Cb = (char*)(ws + OFF_C);
    __hip_bfloat16* SPc = (__hip_bfloat16*)Cb;
    __hip_bfloat16* TPc = (__hip_bfloat16*)(Cb + SPC_BYTES);
    __hip_bfloat16* Wr1 = (__hip_bfloat16*)(Cb + SPC_BYTES + TPC_BYTES);
    __hip_bfloat16* Wr2 = (__hip_bfloat16*)(Cb + SPC_BYTES + TPC_BYTES + WR_BYTES);
    float* Cf = (float*)Cb;
    float* CP  = Cf + CPOFF;
    float* NC  = Cf + NCOFF;
    float* SAT = Cf + SATOFF;

    hipMemsetAsync(ST, 0, (2048 + 131072) * sizeof(float), stream);

    pad_all<<<dim3(16 * 66 * 4 + 16 * 18 * 4 + 512), dim3(256), 0, stream>>>(
        s, t, SPc, TPc, w1, w2, Wr1, Wr2);

    conv_all<<<dim3(64 + 1024), dim3(256), 0, stream>>>(SPc, Wr1, b1, S1, CHS1, CHQ1,
                                                        TPc, Wr2, b2, T2, CHS2, CHQ2);

    bn_t2_stats<<<dim3(16), dim3(256), 0, stream>>>(T2, CHS2, CHQ2, g2, be2, TM, TSD);

    cross_v3<<<dim3(16 * GROUPS), dim3(256), 0, stream>>>(S1, T2, CHS1, CHQ1, g1, be1, CP, Z);
    sat_kernel<<<dim3(32), dim3(256), 0, stream>>>(Z, SAT);
    ncc_kernel<<<dim3(151), dim3(256), 0, stream>>>(CP, SAT, TM, TSD, NC, S3);
    final_kernel<<<dim3(151), dim3(256), 0, stream>>>(NC, S3, w3, b3, g3, be3, w4, b4, (float*)d_out);
}

// Round 14
// 438.045 us; speedup vs baseline: 1.1462x; 1.1462x over previous
//
#include <hip/hip_runtime.h>
#include <hip/hip_bf16.h>

#define EPSV 1e-5f

constexpr int B_ = 16, C_ = 256;
constexpr int OHW_ = 49 * 49;          // 2401
constexpr int NTOT = 256 * 16 * 16;    // 65536
constexpr int GROUPS = 32, CPERG = 8;

typedef short bf16x8 __attribute__((ext_vector_type(8)));
typedef float f32x4 __attribute__((ext_vector_type(4)));

// ---------------- workspace layout (float offsets) ----------------
constexpr size_t OFF_S1 = 0;                               // conv1 out, 16*256*4096 f32
constexpr size_t SZ_S1  = (size_t)16 * 256 * 4096;
constexpr size_t OFF_T2 = OFF_S1 + SZ_S1;                  // conv2 out (bn'd in place)
constexpr size_t SZ_T2  = (size_t)16 * 256 * 256;
constexpr size_t OFF_ST = OFF_T2 + SZ_T2;                  // stats block (2048 f)
constexpr size_t OFF_Z  = OFF_ST + 2048;                   // [2][16][4096] z, z2
constexpr size_t OFF_C  = OFF_Z + 131072;                  // overlaid big region
constexpr size_t SPC_BYTES = (size_t)16 * 66 * 66 * 256 * 2;
constexpr size_t TPC_BYTES = (size_t)16 * 18 * 18 * 256 * 2;
constexpr size_t WR_BYTES  = (size_t)9 * 256 * 256 * 2;
constexpr size_t CPOFF = 0;
constexpr size_t NCOFF = CPOFF + (size_t)GROUPS * 16 * OHW_;
constexpr size_t SATOFF = NCOFF + (size_t)16 * OHW_;

// ---------------- async global->LDS 16B ----------------
__device__ __forceinline__ void gload_lds16(const void* g, void* l) {
    __builtin_amdgcn_global_load_lds((const __attribute__((address_space(1))) unsigned int*)g,
                                     (__attribute__((address_space(3))) unsigned int*)l,
                                     16, 0, 0);
}

// ---------------- pad + NCHW->NHWC + bf16 + weight reorg, merged ----------------
template<int W>
__device__ __forceinline__ void pad_body(int bid, const float* __restrict__ in,
                                         __hip_bfloat16* __restrict__ outp, float* tile)
{
    constexpr int PW = W + 2;
    int icg = bid & 3; bid >>= 2;
    int yp = bid % PW; bid /= PW;
    int b = bid;
    int ic0 = icg * 64;
    int tid = threadIdx.x;
    bool interior = (yp >= 1 && yp <= W);
    if (interior) {
        int y = yp - 1;
        for (int idx = tid; idx < 64 * W; idx += 256) {
            int i = idx / W, x = idx % W;
            tile[i * (W + 1) + x] = in[(((size_t)(b * C_ + ic0 + i)) * W + y) * W + x];
        }
    }
    __syncthreads();
    for (int idx = tid; idx < PW * 16; idx += 256) {
        int xp = idx >> 4, i4 = idx & 15;
        ushort4 v = make_ushort4(0, 0, 0, 0);
        if (interior && xp >= 1 && xp <= W) {
            #pragma unroll
            for (int k = 0; k < 4; ++k) {
                __hip_bfloat16 h = __float2bfloat16(tile[(i4 * 4 + k) * (W + 1) + xp - 1]);
                reinterpret_cast<unsigned short*>(&v)[k] = *reinterpret_cast<unsigned short*>(&h);
            }
        }
        *reinterpret_cast<ushort4*>(&outp[(((size_t)(b * PW) + yp) * PW + xp) * 256 + ic0 + i4 * 4]) = v;
    }
}

__global__ __launch_bounds__(256)
void pad_all(const float* __restrict__ s, const float* __restrict__ t,
             __hip_bfloat16* __restrict__ SPc, __hip_bfloat16* __restrict__ TPc,
             const float* __restrict__ w1, const float* __restrict__ w2,
             __hip_bfloat16* __restrict__ wr1, __hip_bfloat16* __restrict__ wr2)
{
    __shared__ float tile[64 * 65];
    constexpr int NP1 = 16 * 66 * 4, NP2 = 16 * 18 * 4;
    int bid = blockIdx.x;
    if (bid < NP1) { pad_body<64>(bid, s, SPc, tile); return; }
    bid -= NP1;
    if (bid < NP2) { pad_body<16>(bid, t, TPc, tile); return; }
    bid -= NP2;
    const float* w = (bid < 256) ? w1 : w2;
    __hip_bfloat16* wr = (bid < 256) ? wr1 : wr2;
    int idx = (bid & 255) * 256 + threadIdx.x;
    const float* src = w + (size_t)idx * 9;
    #pragma unroll
    for (int t_ = 0; t_ < 9; ++t_)
        wr[(size_t)t_ * 65536 + idx] = __float2bfloat16(src[t_]);
}

// ---------------- conv implicit GEMM MFMA — R9-exact body (single-buf, drain->compute) ----------------
template<int W>
__device__ __forceinline__ void conv_body(
    int logical,
    const __hip_bfloat16* __restrict__ SPc, const __hip_bfloat16* __restrict__ Wr,
    const float* __restrict__ bias, float* __restrict__ out,
    float* __restrict__ csum, float* __restrict__ csq,
    __hip_bfloat16* A_lds, __hip_bfloat16* B_lds)
{
    constexpr int PW = W + 2;
    constexpr int NPIX = W * W;
    constexpr int NT = NPIX / 128;
    int nt = logical % NT; logical /= NT;
    int mt = logical & 1;  logical >>= 1;
    int b  = logical;
    int tid = threadIdx.x;
    int lane = tid & 63;
    int wv = tid >> 6, wm = wv >> 1, wn = wv & 1;
    int oc0 = mt * 128, p0 = nt * 128;

    f32x4 acc[4][4];
    #pragma unroll
    for (int i = 0; i < 4; ++i)
        #pragma unroll
        for (int j = 0; j < 4; ++j)
            #pragma unroll
            for (int r = 0; r < 4; ++r) acc[i][j][r] = 0.f;

    const bf16x8* Af = reinterpret_cast<const bf16x8*>(A_lds);
    const bf16x8* Bf = reinterpret_cast<const bf16x8*>(B_lds);
    int colb = lane >> 4;
    int rA = lane & 15;

    for (int kc = 0; kc < 72; ++kc) {
        int tap = kc >> 3, icc = kc & 7;
        int ic0 = icc * 32;
        int dy = tap / 3, dx = tap - dy * 3;
        __syncthreads();
        #pragma unroll
        for (int it = 0; it < 2; ++it) {
            int sIdx = tid + it * 256;
            int row = sIdx >> 2, seg = sIdx & 3;
            const __hip_bfloat16* srcA =
                Wr + ((size_t)(tap * 256 + oc0 + row)) * 256 + ic0 + seg * 8;
            gload_lds16(srcA, &A_lds[sIdx * 8]);
            int p = p0 + row;
            int y = p / W, x = p % W;
            const __hip_bfloat16* srcB =
                SPc + (((size_t)(b * PW + y + dy)) * PW + x + dx) * 256 + ic0 + seg * 8;
            gload_lds16(srcB, &B_lds[sIdx * 8]);
        }
        asm volatile("s_waitcnt vmcnt(0)" ::: "memory");
        __syncthreads();

        bf16x8 a[4], bb[4];
        #pragma unroll
        for (int mi = 0; mi < 4; ++mi)
            a[mi] = Af[(wm * 64 + mi * 16 + rA) * 4 + colb];
        #pragma unroll
        for (int ni = 0; ni < 4; ++ni)
            bb[ni] = Bf[(wn * 64 + ni * 16 + rA) * 4 + colb];
        #pragma unroll
        for (int mi = 0; mi < 4; ++mi)
            #pragma unroll
            for (int ni = 0; ni < 4; ++ni)
                acc[mi][ni] = __builtin_amdgcn_mfma_f32_16x16x32_bf16(
                    a[mi], bb[ni], acc[mi][ni], 0, 0, 0);
    }

    #pragma unroll
    for (int mi = 0; mi < 4; ++mi) {
        int ocb = oc0 + wm * 64 + mi * 16 + colb * 4;
        #pragma unroll
        for (int r = 0; r < 4; ++r) {
            int oc = ocb + r;
            float bv = bias[oc];
            float* orow = out + ((size_t)(b * C_ + oc)) * NPIX;
            float s_oc = 0.f, q_oc = 0.f;
            #pragma unroll
            for (int ni = 0; ni < 4; ++ni) {
                int px = p0 + wn * 64 + ni * 16 + rA;
                float v = acc[mi][ni][r] + bv;
                orow[px] = v;
                s_oc += v; q_oc += v * v;
            }
            #pragma unroll
            for (int m_ = 1; m_ < 16; m_ <<= 1) {
                s_oc += __shfl_xor(s_oc, m_);
                q_oc += __shfl_xor(q_oc, m_);
            }
            if (rA == 0) {
                atomicAdd(&csum[oc], s_oc);
                atomicAdd(&csq[oc], q_oc);
            }
        }
    }
}

// conv2 blocks FIRST (bid<64): co-resident from t=0, latency hidden under conv1
__global__ __launch_bounds__(256)
void conv_all(const __hip_bfloat16* __restrict__ SPc, const __hip_bfloat16* __restrict__ Wr1,
              const float* __restrict__ b1, float* __restrict__ S1,
              float* __restrict__ CHS1, float* __restrict__ CHQ1,
              const __hip_bfloat16* __restrict__ TPc, const __hip_bfloat16* __restrict__ Wr2,
              const float* __restrict__ b2, float* __restrict__ T2,
              float* __restrict__ CHS2, float* __restrict__ CHQ2)
{
    __shared__ __hip_bfloat16 A_lds[4096];
    __shared__ __hip_bfloat16 B_lds[4096];
    int bid = blockIdx.x;
    if (bid < 64) {
        conv_body<16>(bid, TPc, Wr2, b2, T2, CHS2, CHQ2, A_lds, B_lds);
    } else {
        int l = bid - 64;
        int logical = (l & 7) * 128 + (l >> 3);   // bijective XCD remap (1024 % 8 == 0)
        conv_body<64>(logical, SPc, Wr1, b1, S1, CHS1, CHQ1, A_lds, B_lds);
    }
}

// ---------------- block reduce helper ----------------
__device__ inline void blk_reduce2(float& a, float& q, int tid) {
    #pragma unroll
    for (int off = 32; off > 0; off >>= 1) {
        a += __shfl_down(a, off);
        q += __shfl_down(q, off);
    }
    __shared__ float ra[4], rq[4];
    if ((tid & 63) == 0) { ra[tid >> 6] = a; rq[tid >> 6] = q; }
    __syncthreads();
    if (tid == 0) { a = ra[0] + ra[1] + ra[2] + ra[3]; q = rq[0] + rq[1] + rq[2] + rq[3]; }
}

// ---------------- BN2 normalize + template stats ----------------
__global__ __launch_bounds__(256)
void bn_t2_stats(float* __restrict__ T2, const float* __restrict__ csum,
                 const float* __restrict__ csq, const float* __restrict__ g2,
                 const float* __restrict__ be2, float* __restrict__ tmean,
                 float* __restrict__ ttstd)
{
    __shared__ float SC[256], SH[256];
    int b = blockIdx.x, tid = threadIdx.x;
    {
        float m = csum[tid] * (1.f / 4096.f);
        float v = csq[tid] * (1.f / 4096.f) - m * m;
        float sc = rsqrtf(v + EPSV) * g2[tid];
        SC[tid] = sc; SH[tid] = be2[tid] - m * sc;
    }
    __syncthreads();
    float4* p = reinterpret_cast<float4*>(T2 + (size_t)b * NTOT);
    float s = 0.f, q = 0.f;
    for (int i4 = tid; i4 < NTOT / 4; i4 += 256) {
        int c = i4 >> 6;
        float sc = SC[c], sh = SH[c];
        float4 v = p[i4];
        v.x = v.x * sc + sh; v.y = v.y * sc + sh;
        v.z = v.z * sc + sh; v.w = v.w * sc + sh;
        s += v.x + v.y + v.z + v.w;
        q += v.x * v.x + v.y * v.y + v.z * v.z + v.w * v.w;
        p[i4] = v;
    }
    blk_reduce2(s, q, tid);
    if (tid == 0) {
        float m = s / (float)NTOT;
        tmean[b] = m;
        ttstd[b] = sqrtf(fmaxf(q - (float)NTOT * m * m, 0.f) / (float)(NTOT - 1));
    }
}

// ---------------- cross-correlation + fused z/z2 partials ----------------
__global__ __launch_bounds__(256, 2)
void cross_v3(const float* __restrict__ s1, const float* __restrict__ t2,
              const float* __restrict__ csum, const float* __restrict__ csq,
              const float* __restrict__ g1, const float* __restrict__ be1,
              float* __restrict__ cpart, float* __restrict__ z)
{
    __shared__ float4 spl4[1024];
    __shared__ float tpl[256];
    __shared__ float red[4][64][49];

    int g = blockIdx.x & (GROUPS - 1);
    int b = blockIdx.x / GROUPS;
    int tid = threadIdx.x;
    int phase = tid >> 6;
    int lane = tid & 63;
    int i = lane;
    int i_ld = i < 49 ? i : 48;

    float acc[49];
    #pragma unroll
    for (int j = 0; j < 49; ++j) acc[j] = 0.f;
    float4 zs[4], zq[4];
    #pragma unroll
    for (int k = 0; k < 4; ++k) {
        zs[k] = make_float4(0.f, 0.f, 0.f, 0.f);
        zq[k] = make_float4(0.f, 0.f, 0.f, 0.f);
    }

    #pragma unroll 1
    for (int cc = 0; cc < CPERG; ++cc) {
        int c = g * CPERG + cc;
        float m = csum[c] * (1.f / 65536.f);
        float v = csq[c] * (1.f / 65536.f) - m * m;
        float sc = rsqrtf(v + EPSV) * g1[c];
        float sh = be1[c] - m * sc;
        __syncthreads();
        const float4* sp4 = reinterpret_cast<const float4*>(s1 + ((size_t)(b * C_ + c)) * 4096);
        #pragma unroll
        for (int k = 0; k < 4; ++k) {
            int gidx = tid + k * 256;
            float4 val = sp4[gidx];
            val.x = val.x * sc + sh; val.y = val.y * sc + sh;
            val.z = val.z * sc + sh; val.w = val.w * sc + sh;
            zs[k].x += val.x; zs[k].y += val.y; zs[k].z += val.z; zs[k].w += val.w;
            zq[k].x += val.x * val.x; zq[k].y += val.y * val.y;
            zq[k].z += val.z * val.z; zq[k].w += val.w * val.w;
            int row = gidx >> 4, jg = gidx & 15;
            spl4[row * 16 + (jg ^ (row & 7))] = val;
        }
        tpl[tid] = t2[((size_t)(b * C_ + c)) * 256 + tid];
        __syncthreads();
        #pragma unroll 1
        for (int tyl = 0; tyl < 4; ++tyl) {
            int ty = phase * 4 + tyl;
            int row = i_ld + ty;
            float r_[64];
            #pragma unroll
            for (int jg = 0; jg < 16; ++jg) {
                float4 v4 = spl4[row * 16 + (jg ^ (row & 7))];
                r_[jg * 4 + 0] = v4.x; r_[jg * 4 + 1] = v4.y;
                r_[jg * 4 + 2] = v4.z; r_[jg * 4 + 3] = v4.w;
            }
            float tt[16];
            const float4* tp4 = reinterpret_cast<const float4*>(&tpl[ty * 16]);
            #pragma unroll
            for (int k = 0; k < 4; ++k) {
                float4 tv = tp4[k];
                tt[k * 4 + 0] = tv.x; tt[k * 4 + 1] = tv.y;
                tt[k * 4 + 2] = tv.z; tt[k * 4 + 3] = tv.w;
            }
            #pragma unroll
            for (int tx = 0; tx < 16; ++tx)
                #pragma unroll
                for (int j = 0; j < 49; ++j)
                    acc[j] += tt[tx] * r_[j + tx];
        }
    }
    #pragma unroll
    for (int k = 0; k < 4; ++k) {
        int pxb = (tid + k * 256) * 4;
        float* zb  = z + (size_t)b * 4096 + pxb;
        float* z2b = z + 65536 + (size_t)b * 4096 + pxb;
        atomicAdd(&zb[0], zs[k].x);  atomicAdd(&zb[1], zs[k].y);
        atomicAdd(&zb[2], zs[k].z);  atomicAdd(&zb[3], zs[k].w);
        atomicAdd(&z2b[0], zq[k].x); atomicAdd(&z2b[1], zq[k].y);
        atomicAdd(&z2b[2], zq[k].z); atomicAdd(&z2b[3], zq[k].w);
    }
    __syncthreads();
    if (i < 49) {
        #pragma unroll
        for (int j = 0; j < 49; ++j) red[phase][i][j] = acc[j];
    }
    __syncthreads();
    float* dst = cpart + ((size_t)(g * B_ + b)) * OHW_;
    for (int e = tid; e < OHW_; e += 256) {
        int ii = e / 49, jj = e - ii * 49;
        dst[e] = red[0][ii][jj] + red[1][ii][jj] + red[2][ii][jj] + red[3][ii][jj];
    }
}

// ---------------- integral images ----------------
__global__ __launch_bounds__(256)
void sat_kernel(const float* __restrict__ zin, float* __restrict__ sat)
{
    __shared__ float t[65][66];
    int pl = blockIdx.x;
    int tid = threadIdx.x;
    const float* src = zin + (size_t)pl * 4096;
    for (int idx = tid; idx < 4096; idx += 256) {
        int y = idx >> 6, x = idx & 63;
        t[y + 1][x + 1] = src[idx];
    }
    for (int idx = tid; idx < 65; idx += 256) { t[0][idx] = 0.f; t[idx][0] = 0.f; }
    __syncthreads();
    if (tid < 64) {
        float run = 0.f;
        for (int x = 1; x <= 64; ++x) { run += t[tid + 1][x]; t[tid + 1][x] = run; }
    }
    __syncthreads();
    if (tid < 64) {
        float run = 0.f;
        for (int y = 1; y <= 64; ++y) { run += t[y][tid + 1]; t[y][tid + 1] = run; }
    }
    __syncthreads();
    float* dst = sat + (size_t)pl * 4225;
    for (int idx = tid; idx < 4225; idx += 256) {
        int r = idx / 65, c = idx % 65;
        dst[idx] = t[r][c];
    }
}

// ---------------- NCC assembly via SAT + global stats ----------------
__global__ __launch_bounds__(256)
void ncc_kernel(const float* __restrict__ cpart, const float* __restrict__ sat,
                const float* __restrict__ tmean, const float* __restrict__ ttstd,
                float* __restrict__ ncc, float* __restrict__ s3)
{
    int idx = blockIdx.x * 256 + threadIdx.x;
    float val = 0.f;
    if (idx < B_ * OHW_) {
        int b = idx / OHW_, r = idx - b * OHW_;
        int i = r / 49, j = r - i * 49;
        float cr = 0.f;
        #pragma unroll 4
        for (int g = 0; g < GROUPS; ++g) cr += cpart[((size_t)(g * B_ + b)) * OHW_ + r];
        const float* sz = sat + (size_t)b * 4225;
        const float* sq = sat + (size_t)(16 + b) * 4225;
        int a00 = i * 65 + j, a01 = i * 65 + j + 16;
        int a10 = (i + 16) * 65 + j, a11 = (i + 16) * 65 + j + 16;
        float wsum = sz[a11] - sz[a01] - sz[a10] + sz[a00];
        float wq   = sq[a11] - sq[a01] - sq[a10] + sq[a00];
        float crosst = cr - tmean[b] * wsum;
        float ssvar = fmaxf(wq - wsum * wsum * (1.f / 65536.f), 0.f) * (1.f / 65535.f);
        float ssstd = sqrtf(ssvar);
        val = crosst / (65536.f * ttstd[b] * ssstd);
        ncc[idx] = val;
    }
    float s = val, q = val * val;
    blk_reduce2(s, q, threadIdx.x);
    if (threadIdx.x == 0) { atomicAdd(&s3[0], s); atomicAdd(&s3[1], q); }
}

// ---------------- conv3+BN3+relu+conv4 ----------------
__global__ __launch_bounds__(256)
void final_kernel(const float* __restrict__ ncc, const float* __restrict__ s3,
                  const float* __restrict__ w3, const float* __restrict__ b3,
                  const float* __restrict__ g3, const float* __restrict__ be3,
                  const float* __restrict__ w4, const float* __restrict__ b4,
                  float* __restrict__ out)
{
    int idx = blockIdx.x * 256 + threadIdx.x;
    if (idx >= B_ * OHW_) return;
    constexpr float M = (float)(B_ * OHW_);
    float mn = s3[0] / M;
    float vn = s3[1] / M - mn * mn;
    float W3 = w3[0], B3 = b3[0];
    float my = W3 * mn + B3;
    float vy = W3 * W3 * vn;
    float sc = rsqrtf(vy + EPSV) * g3[0];
    float y = (W3 * ncc[idx] + B3 - my) * sc + be3[0];
    float h = fmaxf(y, 0.f);
    int b = idx / OHW_, r = idx - b * OHW_;
    out[((size_t)(b * 2 + 0)) * OHW_ + r] = h * w4[0] + b4[0];
    out[((size_t)(b * 2 + 1)) * OHW_ + r] = h * w4[1] + b4[1];
}

extern "C" void kernel_launch(void* const* d_in, const int* in_sizes, int n_in,
                              void* d_out, int out_size, void* d_ws, size_t ws_size,
                              hipStream_t stream)
{
    const float* s   = (const float*)d_in[0];
    const float* t   = (const float*)d_in[1];
    const float* w1  = (const float*)d_in[2];
    const float* b1  = (const float*)d_in[3];
    const float* g1  = (const float*)d_in[4];
    const float* be1 = (const float*)d_in[5];
    const float* w2  = (const float*)d_in[6];
    const float* b2  = (const float*)d_in[7];
    const float* g2  = (const float*)d_in[8];
    const float* be2 = (const float*)d_in[9];
    const float* w3  = (const float*)d_in[10];
    const float* b3  = (const float*)d_in[11];
    const float* g3  = (const float*)d_in[12];
    const float* be3 = (const float*)d_in[13];
    const float* w4  = (const float*)d_in[14];
    const float* b4  = (const float*)d_in[15];

    float* ws = (float*)d_ws;
    float* S1 = ws + OFF_S1;
    float* T2 = ws + OFF_T2;
    float* ST = ws + OFF_ST;
    float* CHS1 = ST + 0;
    float* CHQ1 = ST + 256;
    float* CHS2 = ST + 512;
    float* CHQ2 = ST + 768;
    float* S3   = ST + 1024;
    float* TM   = ST + 1040;
    float* TSD  = ST + 1056;
    float* Z    = ws + OFF_Z;

    char* Cb = (char*)(ws + OFF_C);
    __hip_bfloat16* SPc = (__hip_bfloat16*)Cb;
    __hip_bfloat16* TPc = (__hip_bfloat16*)(Cb + SPC_BYTES);
    __hip_bfloat16* Wr1 = (__hip_bfloat16*)(Cb + SPC_BYTES + TPC_BYTES);
    __hip_bfloat16* Wr2 = (__hip_bfloat16*)(Cb + SPC_BYTES + TPC_BYTES + WR_BYTES);
    float* Cf = (float*)Cb;
    float* CP  = Cf + CPOFF;
    float* NC  = Cf + NCOFF;
    float* SAT = Cf + SATOFF;

    hipMemsetAsync(ST, 0, (2048 + 131072) * sizeof(float), stream);

    pad_all<<<dim3(16 * 66 * 4 + 16 * 18 * 4 + 512), dim3(256), 0, stream>>>(
        s, t, SPc, TPc, w1, w2, Wr1, Wr2);

    conv_all<<<dim3(64 + 1024), dim3(256), 0, stream>>>(SPc, Wr1, b1, S1, CHS1, CHQ1,
                                                        TPc, Wr2, b2, T2, CHS2, CHQ2);

    bn_t2_stats<<<dim3(16), dim3(256), 0, stream>>>(T2, CHS2, CHQ2, g2, be2, TM, TSD);

    cross_v3<<<dim3(16 * GROUPS), dim3(256), 0, stream>>>(S1, T2, CHS1, CHQ1, g1, be1, CP, Z);
    sat_kernel<<<dim3(32), dim3(256), 0, stream>>>(Z, SAT);
    ncc_kernel<<<dim3(151), dim3(256), 0, stream>>>(CP, SAT, TM, TSD, NC, S3);
    final_kernel<<<dim3(151), dim3(256), 0, stream>>>(NC, S3, w3, b3, g3, be3, w4, b4, (float*)d_out);
}

// Round 15
// 437.566 us; speedup vs baseline: 1.1474x; 1.0011x over previous
//
#include <hip/hip_runtime.h>
#include <hip/hip_bf16.h>

#define EPSV 1e-5f

constexpr int B_ = 16, C_ = 256;
constexpr int OHW_ = 49 * 49;          // 2401
constexpr int NTOT = 256 * 16 * 16;    // 65536
constexpr int GROUPS = 32, CPERG = 8;

typedef short bf16x8 __attribute__((ext_vector_type(8)));
typedef float f32x4 __attribute__((ext_vector_type(4)));

// ---------------- workspace layout (float offsets) ----------------
constexpr size_t OFF_S1 = 0;                               // conv1 out, 16*256*4096 f32
constexpr size_t SZ_S1  = (size_t)16 * 256 * 4096;
constexpr size_t OFF_T2 = OFF_S1 + SZ_S1;                  // conv2 out (bn'd in place)
constexpr size_t SZ_T2  = (size_t)16 * 256 * 256;
constexpr size_t OFF_ST = OFF_T2 + SZ_T2;                  // stats block (2048 f)
constexpr size_t OFF_Z  = OFF_ST + 2048;                   // [2][16][4096] z, z2
constexpr size_t OFF_C  = OFF_Z + 131072;                  // overlaid big region
constexpr size_t SPC_BYTES = (size_t)16 * 66 * 66 * 256 * 2;
constexpr size_t TPC_BYTES = (size_t)16 * 18 * 18 * 256 * 2;
constexpr size_t WR_BYTES  = (size_t)9 * 256 * 256 * 2;
constexpr size_t CPOFF = 0;
constexpr size_t NCOFF = CPOFF + (size_t)GROUPS * 16 * OHW_;
constexpr size_t SATOFF = NCOFF + (size_t)16 * OHW_;

// ---------------- async global->LDS 16B ----------------
__device__ __forceinline__ void gload_lds16(const void* g, void* l) {
    __builtin_amdgcn_global_load_lds((const __attribute__((address_space(1))) unsigned int*)g,
                                     (__attribute__((address_space(3))) unsigned int*)l,
                                     16, 0, 0);
}

// ---------------- pad + NCHW->NHWC + bf16 + weight reorg, merged ----------------
template<int W>
__device__ __forceinline__ void pad_body(int bid, const float* __restrict__ in,
                                         __hip_bfloat16* __restrict__ outp, float* tile)
{
    constexpr int PW = W + 2;
    int icg = bid & 3; bid >>= 2;
    int yp = bid % PW; bid /= PW;
    int b = bid;
    int ic0 = icg * 64;
    int tid = threadIdx.x;
    bool interior = (yp >= 1 && yp <= W);
    if (interior) {
        int y = yp - 1;
        for (int idx = tid; idx < 64 * W; idx += 256) {
            int i = idx / W, x = idx % W;
            tile[i * (W + 1) + x] = in[(((size_t)(b * C_ + ic0 + i)) * W + y) * W + x];
        }
    }
    __syncthreads();
    for (int idx = tid; idx < PW * 16; idx += 256) {
        int xp = idx >> 4, i4 = idx & 15;
        ushort4 v = make_ushort4(0, 0, 0, 0);
        if (interior && xp >= 1 && xp <= W) {
            #pragma unroll
            for (int k = 0; k < 4; ++k) {
                __hip_bfloat16 h = __float2bfloat16(tile[(i4 * 4 + k) * (W + 1) + xp - 1]);
                reinterpret_cast<unsigned short*>(&v)[k] = *reinterpret_cast<unsigned short*>(&h);
            }
        }
        *reinterpret_cast<ushort4*>(&outp[(((size_t)(b * PW) + yp) * PW + xp) * 256 + ic0 + i4 * 4]) = v;
    }
}

__global__ __launch_bounds__(256)
void pad_all(const float* __restrict__ s, const float* __restrict__ t,
             __hip_bfloat16* __restrict__ SPc, __hip_bfloat16* __restrict__ TPc,
             const float* __restrict__ w1, const float* __restrict__ w2,
             __hip_bfloat16* __restrict__ wr1, __hip_bfloat16* __restrict__ wr2)
{
    __shared__ float tile[64 * 65];
    constexpr int NP1 = 16 * 66 * 4, NP2 = 16 * 18 * 4;
    int bid = blockIdx.x;
    if (bid < NP1) { pad_body<64>(bid, s, SPc, tile); return; }
    bid -= NP1;
    if (bid < NP2) { pad_body<16>(bid, t, TPc, tile); return; }
    bid -= NP2;
    const float* w = (bid < 256) ? w1 : w2;
    __hip_bfloat16* wr = (bid < 256) ? wr1 : wr2;
    int idx = (bid & 255) * 256 + threadIdx.x;
    const float* src = w + (size_t)idx * 9;
    #pragma unroll
    for (int t_ = 0; t_ < 9; ++t_)
        wr[(size_t)t_ * 65536 + idx] = __float2bfloat16(src[t_]);
}

// ---------------- conv implicit GEMM MFMA — R9 body, BK=64 (2 K-steps per barrier) ----------------
template<int W>
__device__ __forceinline__ void conv_body(
    int logical,
    const __hip_bfloat16* __restrict__ SPc, const __hip_bfloat16* __restrict__ Wr,
    const float* __restrict__ bias, float* __restrict__ out,
    float* __restrict__ csum, float* __restrict__ csq,
    __hip_bfloat16* A_lds, __hip_bfloat16* B_lds)   // 8192 elements each (16 KB x2)
{
    constexpr int PW = W + 2;
    constexpr int NPIX = W * W;
    constexpr int NT = NPIX / 128;
    int nt = logical % NT; logical /= NT;
    int mt = logical & 1;  logical >>= 1;
    int b  = logical;
    int tid = threadIdx.x;
    int lane = tid & 63;
    int wv = tid >> 6, wm = wv >> 1, wn = wv & 1;
    int oc0 = mt * 128, p0 = nt * 128;

    f32x4 acc[4][4];
    #pragma unroll
    for (int i = 0; i < 4; ++i)
        #pragma unroll
        for (int j = 0; j < 4; ++j)
            #pragma unroll
            for (int r = 0; r < 4; ++r) acc[i][j][r] = 0.f;

    const bf16x8* Af = reinterpret_cast<const bf16x8*>(A_lds);
    const bf16x8* Bf = reinterpret_cast<const bf16x8*>(B_lds);
    int colb = lane >> 4;
    int rA = lane & 15;

    for (int kk = 0; kk < 36; ++kk) {
        __syncthreads();
        #pragma unroll
        for (int h = 0; h < 2; ++h) {
            int kc = kk * 2 + h;
            int tap = kc >> 3, icc = kc & 7;
            int ic0 = icc * 32;
            int dy = tap / 3, dx = tap - dy * 3;
            #pragma unroll
            for (int it = 0; it < 2; ++it) {
                int sIdx = tid + it * 256;
                int row = sIdx >> 2, seg = sIdx & 3;
                const __hip_bfloat16* srcA =
                    Wr + ((size_t)(tap * 256 + oc0 + row)) * 256 + ic0 + seg * 8;
                gload_lds16(srcA, &A_lds[h * 4096 + sIdx * 8]);
                int p = p0 + row;
                int y = p / W, x = p % W;
                const __hip_bfloat16* srcB =
                    SPc + (((size_t)(b * PW + y + dy)) * PW + x + dx) * 256 + ic0 + seg * 8;
                gload_lds16(srcB, &B_lds[h * 4096 + sIdx * 8]);
            }
        }
        asm volatile("s_waitcnt vmcnt(0)" ::: "memory");
        __syncthreads();

        #pragma unroll
        for (int h = 0; h < 2; ++h) {
            bf16x8 a[4], bb[4];
            #pragma unroll
            for (int mi = 0; mi < 4; ++mi)
                a[mi] = Af[h * 512 + (wm * 64 + mi * 16 + rA) * 4 + colb];
            #pragma unroll
            for (int ni = 0; ni < 4; ++ni)
                bb[ni] = Bf[h * 512 + (wn * 64 + ni * 16 + rA) * 4 + colb];
            #pragma unroll
            for (int mi = 0; mi < 4; ++mi)
                #pragma unroll
                for (int ni = 0; ni < 4; ++ni)
                    acc[mi][ni] = __builtin_amdgcn_mfma_f32_16x16x32_bf16(
                        a[mi], bb[ni], acc[mi][ni], 0, 0, 0);
        }
    }

    #pragma unroll
    for (int mi = 0; mi < 4; ++mi) {
        int ocb = oc0 + wm * 64 + mi * 16 + colb * 4;
        #pragma unroll
        for (int r = 0; r < 4; ++r) {
            int oc = ocb + r;
            float bv = bias[oc];
            float* orow = out + ((size_t)(b * C_ + oc)) * NPIX;
            float s_oc = 0.f, q_oc = 0.f;
            #pragma unroll
            for (int ni = 0; ni < 4; ++ni) {
                int px = p0 + wn * 64 + ni * 16 + rA;
                float v = acc[mi][ni][r] + bv;
                orow[px] = v;
                s_oc += v; q_oc += v * v;
            }
            #pragma unroll
            for (int m_ = 1; m_ < 16; m_ <<= 1) {
                s_oc += __shfl_xor(s_oc, m_);
                q_oc += __shfl_xor(q_oc, m_);
            }
            if (rA == 0) {
                atomicAdd(&csum[oc], s_oc);
                atomicAdd(&csq[oc], q_oc);
            }
        }
    }
}

// conv2 blocks FIRST (bid<64): co-resident from t=0, latency hidden under conv1
__global__ __launch_bounds__(256)
void conv_all(const __hip_bfloat16* __restrict__ SPc, const __hip_bfloat16* __restrict__ Wr1,
              const float* __restrict__ b1, float* __restrict__ S1,
              float* __restrict__ CHS1, float* __restrict__ CHQ1,
              const __hip_bfloat16* __restrict__ TPc, const __hip_bfloat16* __restrict__ Wr2,
              const float* __restrict__ b2, float* __restrict__ T2,
              float* __restrict__ CHS2, float* __restrict__ CHQ2)
{
    __shared__ __hip_bfloat16 A_lds[8192];
    __shared__ __hip_bfloat16 B_lds[8192];
    int bid = blockIdx.x;
    if (bid < 64) {
        conv_body<16>(bid, TPc, Wr2, b2, T2, CHS2, CHQ2, A_lds, B_lds);
    } else {
        int l = bid - 64;
        int logical = (l & 7) * 128 + (l >> 3);   // bijective XCD remap (1024 % 8 == 0)
        conv_body<64>(logical, SPc, Wr1, b1, S1, CHS1, CHQ1, A_lds, B_lds);
    }
}

// ---------------- block reduce helper ----------------
__device__ inline void blk_reduce2(float& a, float& q, int tid) {
    #pragma unroll
    for (int off = 32; off > 0; off >>= 1) {
        a += __shfl_down(a, off);
        q += __shfl_down(q, off);
    }
    __shared__ float ra[4], rq[4];
    if ((tid & 63) == 0) { ra[tid >> 6] = a; rq[tid >> 6] = q; }
    __syncthreads();
    if (tid == 0) { a = ra[0] + ra[1] + ra[2] + ra[3]; q = rq[0] + rq[1] + rq[2] + rq[3]; }
}

// ---------------- BN2 normalize + template stats ----------------
__global__ __launch_bounds__(256)
void bn_t2_stats(float* __restrict__ T2, const float* __restrict__ csum,
                 const float* __restrict__ csq, const float* __restrict__ g2,
                 const float* __restrict__ be2, float* __restrict__ tmean,
                 float* __restrict__ ttstd)
{
    __shared__ float SC[256], SH[256];
    int b = blockIdx.x, tid = threadIdx.x;
    {
        float m = csum[tid] * (1.f / 4096.f);
        float v = csq[tid] * (1.f / 4096.f) - m * m;
        float sc = rsqrtf(v + EPSV) * g2[tid];
        SC[tid] = sc; SH[tid] = be2[tid] - m * sc;
    }
    __syncthreads();
    float4* p = reinterpret_cast<float4*>(T2 + (size_t)b * NTOT);
    float s = 0.f, q = 0.f;
    for (int i4 = tid; i4 < NTOT / 4; i4 += 256) {
        int c = i4 >> 6;
        float sc = SC[c], sh = SH[c];
        float4 v = p[i4];
        v.x = v.x * sc + sh; v.y = v.y * sc + sh;
        v.z = v.z * sc + sh; v.w = v.w * sc + sh;
        s += v.x + v.y + v.z + v.w;
        q += v.x * v.x + v.y * v.y + v.z * v.z + v.w * v.w;
        p[i4] = v;
    }
    blk_reduce2(s, q, tid);
    if (tid == 0) {
        float m = s / (float)NTOT;
        tmean[b] = m;
        ttstd[b] = sqrtf(fmaxf(q - (float)NTOT * m * m, 0.f) / (float)(NTOT - 1));
    }
}

// ---------------- cross-correlation + fused z/z2 partials ----------------
__global__ __launch_bounds__(256, 2)
void cross_v3(const float* __restrict__ s1, const float* __restrict__ t2,
              const float* __restrict__ csum, const float* __restrict__ csq,
              const float* __restrict__ g1, const float* __restrict__ be1,
              float* __restrict__ cpart, float* __restrict__ z)
{
    __shared__ float4 spl4[1024];
    __shared__ float tpl[256];
    __shared__ float red[4][64][49];

    int g = blockIdx.x & (GROUPS - 1);
    int b = blockIdx.x / GROUPS;
    int tid = threadIdx.x;
    int phase = tid >> 6;
    int lane = tid & 63;
    int i = lane;
    int i_ld = i < 49 ? i : 48;

    float acc[49];
    #pragma unroll
    for (int j = 0; j < 49; ++j) acc[j] = 0.f;
    float4 zs[4], zq[4];
    #pragma unroll
    for (int k = 0; k < 4; ++k) {
        zs[k] = make_float4(0.f, 0.f, 0.f, 0.f);
        zq[k] = make_float4(0.f, 0.f, 0.f, 0.f);
    }

    #pragma unroll 1
    for (int cc = 0; cc < CPERG; ++cc) {
        int c = g * CPERG + cc;
        float m = csum[c] * (1.f / 65536.f);
        float v = csq[c] * (1.f / 65536.f) - m * m;
        float sc = rsqrtf(v + EPSV) * g1[c];
        float sh = be1[c] - m * sc;
        __syncthreads();
        const float4* sp4 = reinterpret_cast<const float4*>(s1 + ((size_t)(b * C_ + c)) * 4096);
        #pragma unroll
        for (int k = 0; k < 4; ++k) {
            int gidx = tid + k * 256;
            float4 val = sp4[gidx];
            val.x = val.x * sc + sh; val.y = val.y * sc + sh;
            val.z = val.z * sc + sh; val.w = val.w * sc + sh;
            zs[k].x += val.x; zs[k].y += val.y; zs[k].z += val.z; zs[k].w += val.w;
            zq[k].x += val.x * val.x; zq[k].y += val.y * val.y;
            zq[k].z += val.z * val.z; zq[k].w += val.w * val.w;
            int row = gidx >> 4, jg = gidx & 15;
            spl4[row * 16 + (jg ^ (row & 7))] = val;
        }
        tpl[tid] = t2[((size_t)(b * C_ + c)) * 256 + tid];
        __syncthreads();
        #pragma unroll 1
        for (int tyl = 0; tyl < 4; ++tyl) {
            int ty = phase * 4 + tyl;
            int row = i_ld + ty;
            float r_[64];
            #pragma unroll
            for (int jg = 0; jg < 16; ++jg) {
                float4 v4 = spl4[row * 16 + (jg ^ (row & 7))];
                r_[jg * 4 + 0] = v4.x; r_[jg * 4 + 1] = v4.y;
                r_[jg * 4 + 2] = v4.z; r_[jg * 4 + 3] = v4.w;
            }
            float tt[16];
            const float4* tp4 = reinterpret_cast<const float4*>(&tpl[ty * 16]);
            #pragma unroll
            for (int k = 0; k < 4; ++k) {
                float4 tv = tp4[k];
                tt[k * 4 + 0] = tv.x; tt[k * 4 + 1] = tv.y;
                tt[k * 4 + 2] = tv.z; tt[k * 4 + 3] = tv.w;
            }
            #pragma unroll
            for (int tx = 0; tx < 16; ++tx)
                #pragma unroll
                for (int j = 0; j < 49; ++j)
                    acc[j] += tt[tx] * r_[j + tx];
        }
    }
    #pragma unroll
    for (int k = 0; k < 4; ++k) {
        int pxb = (tid + k * 256) * 4;
        float* zb  = z + (size_t)b * 4096 + pxb;
        float* z2b = z + 65536 + (size_t)b * 4096 + pxb;
        atomicAdd(&zb[0], zs[k].x);  atomicAdd(&zb[1], zs[k].y);
        atomicAdd(&zb[2], zs[k].z);  atomicAdd(&zb[3], zs[k].w);
        atomicAdd(&z2b[0], zq[k].x); atomicAdd(&z2b[1], zq[k].y);
        atomicAdd(&z2b[2], zq[k].z); atomicAdd(&z2b[3], zq[k].w);
    }
    __syncthreads();
    if (i < 49) {
        #pragma unroll
        for (int j = 0; j < 49; ++j) red[phase][i][j] = acc[j];
    }
    __syncthreads();
    float* dst = cpart + ((size_t)(g * B_ + b)) * OHW_;
    for (int e = tid; e < OHW_; e += 256) {
        int ii = e / 49, jj = e - ii * 49;
        dst[e] = red[0][ii][jj] + red[1][ii][jj] + red[2][ii][jj] + red[3][ii][jj];
    }
}

// ---------------- integral images ----------------
__global__ __launch_bounds__(256)
void sat_kernel(const float* __restrict__ zin, float* __restrict__ sat)
{
    __shared__ float t[65][66];
    int pl = blockIdx.x;
    int tid = threadIdx.x;
    const float* src = zin + (size_t)pl * 4096;
    for (int idx = tid; idx < 4096; idx += 256) {
        int y = idx >> 6, x = idx & 63;
        t[y + 1][x + 1] = src[idx];
    }
    for (int idx = tid; idx < 65; idx += 256) { t[0][idx] = 0.f; t[idx][0] = 0.f; }
    __syncthreads();
    if (tid < 64) {
        float run = 0.f;
        for (int x = 1; x <= 64; ++x) { run += t[tid + 1][x]; t[tid + 1][x] = run; }
    }
    __syncthreads();
    if (tid < 64) {
        float run = 0.f;
        for (int y = 1; y <= 64; ++y) { run += t[y][tid + 1]; t[y][tid + 1] = run; }
    }
    __syncthreads();
    float* dst = sat + (size_t)pl * 4225;
    for (int idx = tid; idx < 4225; idx += 256) {
        int r = idx / 65, c = idx % 65;
        dst[idx] = t[r][c];
    }
}

// ---------------- NCC assembly via SAT + global stats ----------------
__global__ __launch_bounds__(256)
void ncc_kernel(const float* __restrict__ cpart, const float* __restrict__ sat,
                const float* __restrict__ tmean, const float* __restrict__ ttstd,
                float* __restrict__ ncc, float* __restrict__ s3)
{
    int idx = blockIdx.x * 256 + threadIdx.x;
    float val = 0.f;
    if (idx < B_ * OHW_) {
        int b = idx / OHW_, r = idx - b * OHW_;
        int i = r / 49, j = r - i * 49;
        float cr = 0.f;
        #pragma unroll 4
        for (int g = 0; g < GROUPS; ++g) cr += cpart[((size_t)(g * B_ + b)) * OHW_ + r];
        const float* sz = sat + (size_t)b * 4225;
        const float* sq = sat + (size_t)(16 + b) * 4225;
        int a00 = i * 65 + j, a01 = i * 65 + j + 16;
        int a10 = (i + 16) * 65 + j, a11 = (i + 16) * 65 + j + 16;
        float wsum = sz[a11] - sz[a01] - sz[a10] + sz[a00];
        float wq   = sq[a11] - sq[a01] - sq[a10] + sq[a00];
        float crosst = cr - tmean[b] * wsum;
        float ssvar = fmaxf(wq - wsum * wsum * (1.f / 65536.f), 0.f) * (1.f / 65535.f);
        float ssstd = sqrtf(ssvar);
        val = crosst / (65536.f * ttstd[b] * ssstd);
        ncc[idx] = val;
    }
    float s = val, q = val * val;
    blk_reduce2(s, q, threadIdx.x);
    if (threadIdx.x == 0) { atomicAdd(&s3[0], s); atomicAdd(&s3[1], q); }
}

// ---------------- conv3+BN3+relu+conv4 ----------------
__global__ __launch_bounds__(256)
void final_kernel(const float* __restrict__ ncc, const float* __restrict__ s3,
                  const float* __restrict__ w3, const float* __restrict__ b3,
                  const float* __restrict__ g3, const float* __restrict__ be3,
                  const float* __restrict__ w4, const float* __restrict__ b4,
                  float* __restrict__ out)
{
    int idx = blockIdx.x * 256 + threadIdx.x;
    if (idx >= B_ * OHW_) return;
    constexpr float M = (float)(B_ * OHW_);
    float mn = s3[0] / M;
    float vn = s3[1] / M - mn * mn;
    float W3 = w3[0], B3 = b3[0];
    float my = W3 * mn + B3;
    float vy = W3 * W3 * vn;
    float sc = rsqrtf(vy + EPSV) * g3[0];
    float y = (W3 * ncc[idx] + B3 - my) * sc + be3[0];
    float h = fmaxf(y, 0.f);
    int b = idx / OHW_, r = idx - b * OHW_;
    out[((size_t)(b * 2 + 0)) * OHW_ + r] = h * w4[0] + b4[0];
    out[((size_t)(b * 2 + 1)) * OHW_ + r] = h * w4[1] + b4[1];
}

extern "C" void kernel_launch(void* const* d_in, const int* in_sizes, int n_in,
                              void* d_out, int out_size, void* d_ws, size_t ws_size,
                              hipStream_t stream)
{
    const float* s   = (const float*)d_in[0];
    const float* t   = (const float*)d_in[1];
    const float* w1  = (const float*)d_in[2];
    const float* b1  = (const float*)d_in[3];
    const float* g1  = (const float*)d_in[4];
    const float* be1 = (const float*)d_in[5];
    const float* w2  = (const float*)d_in[6];
    const float* b2  = (const float*)d_in[7];
    const float* g2  = (const float*)d_in[8];
    const float* be2 = (const float*)d_in[9];
    const float* w3  = (const float*)d_in[10];
    const float* b3  = (const float*)d_in[11];
    const float* g3  = (const float*)d_in[12];
    const float* be3 = (const float*)d_in[13];
    const float* w4  = (const float*)d_in[14];
    const float* b4  = (const float*)d_in[15];

    float* ws = (float*)d_ws;
    float* S1 = ws + OFF_S1;
    float* T2 = ws + OFF_T2;
    float* ST = ws + OFF_ST;
    float* CHS1 = ST + 0;
    float* CHQ1 = ST + 256;
    float* CHS2 = ST + 512;
    float* CHQ2 = ST + 768;
    float* S3   = ST + 1024;
    float* TM   = ST + 1040;
    float* TSD  = ST + 1056;
    float* Z    = ws + OFF_Z;

    char* Cb = (char*)(ws + OFF_C);
    __hip_bfloat16* SPc = (__hip_bfloat16*)Cb;
    __hip_bfloat16* TPc = (__hip_bfloat16*)(Cb + SPC_BYTES);
    __hip_bfloat16* Wr1 = (__hip_bfloat16*)(Cb + SPC_BYTES + TPC_BYTES);
    __hip_bfloat16* Wr2 = (__hip_bfloat16*)(Cb + SPC_BYTES + TPC_BYTES + WR_BYTES);
    float* Cf = (float*)Cb;
    float* CP  = Cf + CPOFF;
    float* NC  = Cf + NCOFF;
    float* SAT = Cf + SATOFF;

    hipMemsetAsync(ST, 0, (2048 + 131072) * sizeof(float), stream);

    pad_all<<<dim3(16 * 66 * 4 + 16 * 18 * 4 + 512), dim3(256), 0, stream>>>(
        s, t, SPc, TPc, w1, w2, Wr1, Wr2);

    conv_all<<<dim3(64 + 1024), dim3(256), 0, stream>>>(SPc, Wr1, b1, S1, CHS1, CHQ1,
                                                        TPc, Wr2, b2, T2, CHS2, CHQ2);

    bn_t2_stats<<<dim3(16), dim3(256), 0, stream>>>(T2, CHS2, CHQ2, g2, be2, TM, TSD);

    cross_v3<<<dim3(16 * GROUPS), dim3(256), 0, stream>>>(S1, T2, CHS1, CHQ1, g1, be1, CP, Z);
    sat_kernel<<<dim3(32), dim3(256), 0, stream>>>(Z, SAT);
    ncc_kernel<<<dim3(151), dim3(256), 0, stream>>>(CP, SAT, TM, TSD, NC, S3);
    final_kernel<<<dim3(151), dim3(256), 0, stream>>>(NC, S3, w3, b3, g3, be3, w4, b4, (float*)d_out);
}